// Round 1
// baseline (422.917 us; speedup 1.0000x reference)
//
#include <hip/hip_runtime.h>

typedef __attribute__((ext_vector_type(4))) float   floatx4;
typedef __attribute__((ext_vector_type(8))) __bf16  bf16x8;
typedef unsigned short ushort_t;
typedef __attribute__((ext_vector_type(8))) ushort_t ushortx8;

typedef const unsigned int __attribute__((address_space(1)))* gptr_t;
typedef unsigned int __attribute__((address_space(3)))* lptr_t;

#define NIMG 32
#define H    112
#define W    112
#define CIN  128
#define COUT 256
#define HP   114
#define WP   114

#define BM 128
#define BN 128
#define BK 32
#define KSTEPS 36   // K = 3*3*128 = 1152 = 36*32

// ---------- fp32 -> bf16 (round-to-nearest-even) ----------
__device__ __forceinline__ ushort_t f32_to_bf16(float f) {
    unsigned u = __float_as_uint(f);
    unsigned r = 0x7fffu + ((u >> 16) & 1u);
    return (ushort_t)((u + r) >> 16);
}

// ---------- Prepass 1: convert + zero-pad input to [32][114][114][128] bf16 ----------
// one thread = 8 channels (16B store). total chunks = 32*114*114*16 = 6,653,952
__global__ __launch_bounds__(256) void prepad_input(const float* __restrict__ in,
                                                    ushort_t* __restrict__ pad) {
    int t   = blockIdx.x * 256 + threadIdx.x;
    int ic8 = t & 15;
    int sp  = t >> 4;
    int iw  = sp % WP;
    int sp2 = sp / WP;
    int ih  = sp2 % HP;
    int n   = sp2 / HP;
    ushortx8 v;
    if (ih >= 1 && ih <= H && iw >= 1 && iw <= W) {
        const float* src = in + ((size_t)((n * H + (ih - 1)) * W + (iw - 1))) * CIN + ic8 * 8;
        floatx4 a = *reinterpret_cast<const floatx4*>(src);
        floatx4 b = *reinterpret_cast<const floatx4*>(src + 4);
#pragma unroll
        for (int j = 0; j < 4; ++j) { v[j] = f32_to_bf16(a[j]); v[4 + j] = f32_to_bf16(b[j]); }
    } else {
#pragma unroll
        for (int j = 0; j < 8; ++j) v[j] = 0;
    }
    reinterpret_cast<ushortx8*>(pad)[t] = v;
}

// ---------- Prepass 2: kernel (3,3,128,256) fp32 HWIO -> bf16 [kh][kw][oc][ic] ----------
// total = 3*3*256*128 = 294,912 elements
__global__ __launch_bounds__(256) void wtrans(const float* __restrict__ k,
                                              ushort_t* __restrict__ wt) {
    int t    = blockIdx.x * 256 + threadIdx.x;
    int ic   = t & 127;
    int oc   = (t >> 7) & 255;
    int khkw = t >> 15;
    wt[t] = f32_to_bf16(k[((size_t)(khkw * CIN + ic)) * COUT + oc]);
}

// ---------- Main: implicit-GEMM bf16 MFMA conv ----------
// grid = (M/BM) * 2 = 3136*2 = 6272 blocks of 256 threads (4 waves, 2x2 of 64x64)
__global__ __launch_bounds__(256) void conv_mfma(const ushort_t* __restrict__ pad,
                                                 const ushort_t* __restrict__ wt,
                                                 const float* __restrict__ bias,
                                                 float* __restrict__ out) {
    __shared__ __align__(16) ushort_t As[BM * BK];  // [m][k]
    __shared__ __align__(16) ushort_t Bs[BN * BK];  // [oc][k]

    const int tid  = threadIdx.x;
    const int wid  = tid >> 6;
    const int lane = tid & 63;
    const int bm   = blockIdx.x >> 1;
    const int bn   = blockIdx.x & 1;

    // --- staging: each wave fills 2x 1KB LDS chunks for A and for B ---
    // chunk i: rows [wid*32 + i*16, +16), lane covers row = base + lane/4, kchunk = lane%4
    const int rbase = wid * 32 + (lane >> 2);
    const int kc    = (lane & 3) * 8;

    const ushort_t* aptr[2];
#pragma unroll
    for (int i = 0; i < 2; ++i) {
        int m  = bm * BM + rbase + i * 16;
        int n  = m / (H * W);
        int r  = m % (H * W);
        int oh = r / W;
        int ow = r % W;
        aptr[i] = pad + ((size_t)((n * HP + oh) * WP + ow)) * CIN + kc;
    }
    const ushort_t* bptr[2];
#pragma unroll
    for (int i = 0; i < 2; ++i) {
        int ocr = bn * BN + rbase + i * 16;
        bptr[i] = wt + (size_t)ocr * CIN + kc;
    }
    ushort_t* asd[2];
    ushort_t* bsd[2];
#pragma unroll
    for (int i = 0; i < 2; ++i) {
        asd[i] = As + (wid * 2 + i) * 512;  // 1024 B per instruction slot
        bsd[i] = Bs + (wid * 2 + i) * 512;
    }

    // --- compute-side fragment offsets ---
    const int wr   = wid >> 1, wc = wid & 1;
    const int aoff = (wr * 64 + (lane & 15)) * BK + (lane >> 4) * 8;
    const int boff = (wc * 64 + (lane & 15)) * BK + (lane >> 4) * 8;

    floatx4 acc[4][4];
#pragma unroll
    for (int i = 0; i < 4; ++i)
#pragma unroll
        for (int j = 0; j < 4; ++j) acc[i][j] = (floatx4)0.0f;

    for (int kt = 0; kt < KSTEPS; ++kt) {
        const int kh   = kt / 12;
        const int kw   = (kt >> 2) % 3;
        const int ic0  = (kt & 3) * 32;
        const int offA = (kh * WP + kw) * CIN + ic0;
        const int offB = (kh * 3 + kw) * COUT * CIN + ic0;
#pragma unroll
        for (int i = 0; i < 2; ++i) {
            __builtin_amdgcn_global_load_lds((gptr_t)(aptr[i] + offA), (lptr_t)(asd[i]), 16, 0, 0);
            __builtin_amdgcn_global_load_lds((gptr_t)(bptr[i] + offB), (lptr_t)(bsd[i]), 16, 0, 0);
        }
        __syncthreads();

        bf16x8 af[4], bfr[4];
#pragma unroll
        for (int mi = 0; mi < 4; ++mi)
            af[mi] = *reinterpret_cast<const bf16x8*>(As + aoff + mi * 16 * BK);
#pragma unroll
        for (int ni = 0; ni < 4; ++ni)
            bfr[ni] = *reinterpret_cast<const bf16x8*>(Bs + boff + ni * 16 * BK);
#pragma unroll
        for (int mi = 0; mi < 4; ++mi)
#pragma unroll
            for (int ni = 0; ni < 4; ++ni)
                acc[mi][ni] = __builtin_amdgcn_mfma_f32_16x16x32_bf16(af[mi], bfr[ni], acc[mi][ni], 0, 0, 0);
        __syncthreads();
    }

    // --- epilogue: verified C/D mapping col=lane&15, row=(lane>>4)*4+reg ---
    const int col0 = bn * BN + wc * 64 + (lane & 15);
    const int row0 = bm * BM + wr * 64 + (lane >> 4) * 4;
#pragma unroll
    for (int ni = 0; ni < 4; ++ni) {
        const float bv = bias[col0 + ni * 16];
#pragma unroll
        for (int mi = 0; mi < 4; ++mi) {
#pragma unroll
            for (int r = 0; r < 4; ++r) {
                out[(size_t)(row0 + mi * 16 + r) * COUT + (col0 + ni * 16)] = acc[mi][ni][r] + bv;
            }
        }
    }
}

extern "C" void kernel_launch(void* const* d_in, const int* in_sizes, int n_in,
                              void* d_out, int out_size, void* d_ws, size_t ws_size,
                              hipStream_t stream) {
    const float* input = (const float*)d_in[0];
    const float* kern  = (const float*)d_in[1];
    const float* bias  = (const float*)d_in[2];
    float* out         = (float*)d_out;

    ushort_t* pad = (ushort_t*)d_ws;                          // 106,463,232 B
    ushort_t* wt  = pad + (size_t)NIMG * HP * WP * CIN;       // + 589,824 B

    prepad_input<<<25992, 256, 0, stream>>>(input, pad);      // 6,653,952 / 256
    wtrans<<<1152, 256, 0, stream>>>(kern, wt);               // 294,912 / 256
    conv_mfma<<<6272, 256, 0, stream>>>(pad, wt, bias, out);  // 3136 M-blocks * 2 N-blocks
}

// Round 2
// 363.766 us; speedup vs baseline: 1.1626x; 1.1626x over previous
//
#include <hip/hip_runtime.h>

typedef __attribute__((ext_vector_type(4))) float   floatx4;
typedef __attribute__((ext_vector_type(8))) __bf16  bf16x8;
typedef unsigned short ushort_t;
typedef __attribute__((ext_vector_type(8))) ushort_t ushortx8;

typedef const unsigned int __attribute__((address_space(1)))* gptr_t;
typedef unsigned int __attribute__((address_space(3)))* lptr_t;

#define NIMG 32
#define H    112
#define W    112
#define CIN  128
#define COUT 256
#define HP   114
#define WP   114
#define HW   12544      // H*W, = 49*256 so every 256-row tile stays in one image

#define BM 256
#define BN 256
#define BK 64
#define NT 18           // K = 3*3*128 = 1152 = 18*64

// ---------- fp32 -> bf16 (round-to-nearest-even) ----------
__device__ __forceinline__ ushort_t f32_to_bf16(float f) {
    unsigned u = __float_as_uint(f);
    unsigned r = 0x7fffu + ((u >> 16) & 1u);
    return (ushort_t)((u + r) >> 16);
}

// ---------- Prepass 1: convert + zero-pad input to [32][114][114][128] bf16 ----------
__global__ __launch_bounds__(256) void prepad_input(const float* __restrict__ in,
                                                    ushort_t* __restrict__ pad) {
    int t   = blockIdx.x * 256 + threadIdx.x;
    int ic8 = t & 15;
    int sp  = t >> 4;
    int iw  = sp % WP;
    int sp2 = sp / WP;
    int ih  = sp2 % HP;
    int n   = sp2 / HP;
    ushortx8 v;
    if (ih >= 1 && ih <= H && iw >= 1 && iw <= W) {
        const float* src = in + ((size_t)((n * H + (ih - 1)) * W + (iw - 1))) * CIN + ic8 * 8;
        floatx4 a = *reinterpret_cast<const floatx4*>(src);
        floatx4 b = *reinterpret_cast<const floatx4*>(src + 4);
#pragma unroll
        for (int j = 0; j < 4; ++j) { v[j] = f32_to_bf16(a[j]); v[4 + j] = f32_to_bf16(b[j]); }
    } else {
#pragma unroll
        for (int j = 0; j < 8; ++j) v[j] = 0;
    }
    reinterpret_cast<ushortx8*>(pad)[t] = v;
}

// ---------- Prepass 2: kernel (3,3,128,256) fp32 HWIO -> bf16 [kh][kw][oc][ic] ----------
__global__ __launch_bounds__(256) void wtrans(const float* __restrict__ k,
                                              ushort_t* __restrict__ wt) {
    int t    = blockIdx.x * 256 + threadIdx.x;
    int ic   = t & 127;
    int oc   = (t >> 7) & 255;
    int khkw = t >> 15;
    wt[t] = f32_to_bf16(k[((size_t)(khkw * CIN + ic)) * COUT + oc]);
}

// ---------- Main: 256x256 8-phase implicit-GEMM bf16 MFMA conv ----------
// grid = M/256 = 1568 blocks of 512 threads (8 waves, 2M x 4N; per-wave 128x64 output)
// LDS: buf[2] x { A[2 halves][128][64], B[2 halves][128][64] } bf16 = 128 KiB
// K-tile t: 4 phases. Phase q: reads A-frags rf={2q,2q+1} (+ all B-frags at q0),
// stages one half-tile (A(t+1) at q0/q1 -> buf[nxt]; B(t+2) at q2/q3 -> buf[cur]),
// barrier, 16 MFMA under setprio, [vmcnt(4) at q3], barrier.  Never vmcnt(0) in steady state.
// LDS swizzle: physical chunk c holds logical chunk c^(row&7); both-sides via
// pre-swizzled per-lane global source + swizzled ds_read (linear global_load_lds dest).

__device__ __forceinline__ int aoffK(int t) {
    int tap = t >> 1;
    return ((tap / 3) * WP + (tap % 3)) * CIN + (t & 1) * 64;
}
__device__ __forceinline__ int boffK(int t) {
    int tap = t >> 1;
    return tap * (COUT * CIN) + (t & 1) * 64;
}

__global__ __launch_bounds__(512, 2) void conv_mfma8(const ushort_t* __restrict__ pad,
                                                     const ushort_t* __restrict__ wt,
                                                     const float* __restrict__ bias,
                                                     float* __restrict__ out) {
    __shared__ __align__(16) ushort_t lds[65536];   // 128 KiB

    const int tid  = threadIdx.x;
    const int wid  = tid >> 6;
    const int lane = tid & 63;
    const int wm   = wid >> 2;       // 0..1 : 128-row band
    const int wn   = wid & 3;        // 0..3 : 64-col band
    const int bid  = blockIdx.x;
    const int bm   = (bid & 7) * 196 + (bid >> 3);   // XCD swizzle, 1568 % 8 == 0

    // ---- staging source pointers (pre-swizzled per-lane global addresses) ----
    const int trow = tid >> 3;              // 0..63 : row within a 64-row issue slice
    const int lc   = (tid & 7) ^ (trow & 7);  // logical chunk for this thread's physical slot

    const ushort_t* srcA[4];                // i = half*2 + issue  (rows i*64+trow of the 256-row tile)
    const ushort_t* srcB[4];
#pragma unroll
    for (int i = 0; i < 4; ++i) {
        int m  = bm * BM + i * 64 + trow;
        int n  = m / HW;
        int r  = m % HW;
        int oh = r / W;
        int ow = r % W;
        srcA[i] = pad + ((size_t)((n * HP + oh) * WP + ow)) * CIN + lc * 8;
        int oc = i * 64 + trow;
        srcB[i] = wt + (size_t)oc * CIN + lc * 8;
    }
    const int dstSlot = wid * 512;          // ushort elems within an issue slice (wave-uniform)

#define STAGE_A(tile, half)                                                                         \
    { int _o = aoffK(tile); int _b = ((tile) & 1) * 32768 + (half) * 8192 + dstSlot;                \
      __builtin_amdgcn_global_load_lds((gptr_t)(srcA[(half)*2+0] + _o), (lptr_t)&lds[_b       ], 16, 0, 0); \
      __builtin_amdgcn_global_load_lds((gptr_t)(srcA[(half)*2+1] + _o), (lptr_t)&lds[_b + 4096], 16, 0, 0); }
#define STAGE_B(tile, half)                                                                         \
    { int _o = boffK(tile); int _b = ((tile) & 1) * 32768 + 16384 + (half) * 8192 + dstSlot;        \
      __builtin_amdgcn_global_load_lds((gptr_t)(srcB[(half)*2+0] + _o), (lptr_t)&lds[_b       ], 16, 0, 0); \
      __builtin_amdgcn_global_load_lds((gptr_t)(srcB[(half)*2+1] + _o), (lptr_t)&lds[_b + 4096], 16, 0, 0); }

    // ---- read-side constants (ushort elems; row = 64 elems = 128 B) ----
    const int aBase = wm * 8192 + (lane & 15) * 64;
    const int bBase = 16384 + (wn >> 1) * 8192 + ((wn & 1) * 64 + (lane & 15)) * 64;
    int cOff[2];
#pragma unroll
    for (int ks = 0; ks < 2; ++ks)
        cOff[ks] = ((ks * 4 + (lane >> 4)) ^ (lane & 7)) * 8;

    floatx4 acc[8][4];
#pragma unroll
    for (int i = 0; i < 8; ++i)
#pragma unroll
        for (int j = 0; j < 4; ++j) acc[i][j] = (floatx4)0.0f;

    // ---- prologue: tile0 fully + B(tile1); wait tile0 (allow B(1)'s 4 loads in flight) ----
    STAGE_A(0, 0); STAGE_A(0, 1); STAGE_B(0, 0); STAGE_B(0, 1);
    STAGE_B(1, 0); STAGE_B(1, 1);
    asm volatile("s_waitcnt vmcnt(4)" ::: "memory");
    __builtin_amdgcn_s_barrier();

    // ---- main loop ----
    for (int t = 0; t < NT; ++t) {
        const int bufb = (t & 1) * 32768;
        bf16x8 bfr[4][2];
#pragma unroll
        for (int q = 0; q < 4; ++q) {
            bf16x8 af[2][2];
#pragma unroll
            for (int rfl = 0; rfl < 2; ++rfl)
#pragma unroll
                for (int ks = 0; ks < 2; ++ks)
                    af[rfl][ks] = *reinterpret_cast<const bf16x8*>(&lds[bufb + aBase + (2 * q + rfl) * 1024 + cOff[ks]]);
            if (q == 0) {
#pragma unroll
                for (int cf = 0; cf < 4; ++cf)
#pragma unroll
                    for (int ks = 0; ks < 2; ++ks)
                        bfr[cf][ks] = *reinterpret_cast<const bf16x8*>(&lds[bufb + bBase + cf * 1024 + cOff[ks]]);
            }
            if (q == 0 && t + 1 < NT) STAGE_A(t + 1, 0);
            if (q == 1 && t + 1 < NT) STAGE_A(t + 1, 1);
            if (q == 2 && t + 2 < NT) STAGE_B(t + 2, 0);
            if (q == 3 && t + 2 < NT) STAGE_B(t + 2, 1);
            __builtin_amdgcn_s_barrier();
            __builtin_amdgcn_s_setprio(1);
#pragma unroll
            for (int rfl = 0; rfl < 2; ++rfl)
#pragma unroll
                for (int cf = 0; cf < 4; ++cf)
#pragma unroll
                    for (int ks = 0; ks < 2; ++ks)
                        acc[2 * q + rfl][cf] = __builtin_amdgcn_mfma_f32_16x16x32_bf16(
                            af[rfl][ks], bfr[cf][ks], acc[2 * q + rfl][cf], 0, 0, 0);
            __builtin_amdgcn_s_setprio(0);
            if (q == 3) {
                if (t < NT - 2)       { asm volatile("s_waitcnt vmcnt(4)" ::: "memory"); }
                else if (t == NT - 2) { asm volatile("s_waitcnt vmcnt(0)" ::: "memory"); }
            }
            __builtin_amdgcn_s_barrier();
        }
    }

    // ---- epilogue: C/D map col=lane&15, row=(lane>>4)*4+reg ----
    const int col0 = wn * 64 + (lane & 15);
    const int row0 = bm * BM + wm * 128 + (lane >> 4) * 4;
    float bv[4];
#pragma unroll
    for (int cf = 0; cf < 4; ++cf) bv[cf] = bias[col0 + cf * 16];
#pragma unroll
    for (int rf = 0; rf < 8; ++rf)
#pragma unroll
        for (int cf = 0; cf < 4; ++cf)
#pragma unroll
            for (int r = 0; r < 4; ++r)
                out[(size_t)(row0 + rf * 16 + r) * COUT + col0 + cf * 16] = acc[rf][cf][r] + bv[cf];
#undef STAGE_A
#undef STAGE_B
}

extern "C" void kernel_launch(void* const* d_in, const int* in_sizes, int n_in,
                              void* d_out, int out_size, void* d_ws, size_t ws_size,
                              hipStream_t stream) {
    const float* input = (const float*)d_in[0];
    const float* kern  = (const float*)d_in[1];
    const float* bias  = (const float*)d_in[2];
    float* out         = (float*)d_out;

    ushort_t* pad = (ushort_t*)d_ws;                          // 106,463,232 B
    ushort_t* wt  = pad + (size_t)NIMG * HP * WP * CIN;       // + 589,824 B

    prepad_input<<<25992, 256, 0, stream>>>(input, pad);
    wtrans<<<1152, 256, 0, stream>>>(kern, wt);
    conv_mfma8<<<1568, 512, 0, stream>>>(pad, wt, bias, out); // 1568 = 401408/256, %8==0
}

// Round 5
// 362.274 us; speedup vs baseline: 1.1674x; 1.0041x over previous
//
#include <hip/hip_runtime.h>

typedef __attribute__((ext_vector_type(4))) float   floatx4;
typedef __attribute__((ext_vector_type(8))) __bf16  bf16x8;
typedef unsigned short ushort_t;
typedef __attribute__((ext_vector_type(8))) ushort_t ushortx8;

typedef const unsigned int __attribute__((address_space(1)))* gptr_t;
typedef unsigned int __attribute__((address_space(3)))* lptr_t;

#define NIMG 32
#define H    112
#define W    112
#define CIN  128
#define COUT 256
#define HP   114
#define WP   114
#define HW   12544      // H*W, = 49*256 so every 256-row tile stays in one image

#define BM 256
#define BN 256
#define BK 64
#define NT 18           // K = 3*3*128 = 1152 = 18*64

// ---------- fp32 -> bf16 (round-to-nearest-even) ----------
__device__ __forceinline__ ushort_t f32_to_bf16(float f) {
    unsigned u = __float_as_uint(f);
    unsigned r = 0x7fffu + ((u >> 16) & 1u);
    return (ushort_t)((u + r) >> 16);
}

// ---------- Prepass 1: convert + zero-pad input to [32][114][114][128] bf16 ----------
__global__ __launch_bounds__(256) void prepad_input(const float* __restrict__ in,
                                                    ushort_t* __restrict__ pad) {
    int t   = blockIdx.x * 256 + threadIdx.x;
    int ic8 = t & 15;
    int sp  = t >> 4;
    int iw  = sp % WP;
    int sp2 = sp / WP;
    int ih  = sp2 % HP;
    int n   = sp2 / HP;
    ushortx8 v;
    if (ih >= 1 && ih <= H && iw >= 1 && iw <= W) {
        const float* src = in + ((size_t)((n * H + (ih - 1)) * W + (iw - 1))) * CIN + ic8 * 8;
        floatx4 a = *reinterpret_cast<const floatx4*>(src);
        floatx4 b = *reinterpret_cast<const floatx4*>(src + 4);
#pragma unroll
        for (int j = 0; j < 4; ++j) { v[j] = f32_to_bf16(a[j]); v[4 + j] = f32_to_bf16(b[j]); }
    } else {
#pragma unroll
        for (int j = 0; j < 8; ++j) v[j] = 0;
    }
    reinterpret_cast<ushortx8*>(pad)[t] = v;
}

// ---------- Prepass 2: kernel (3,3,128,256) fp32 HWIO -> bf16 [kh][kw][oc][ic] ----------
__global__ __launch_bounds__(256) void wtrans(const float* __restrict__ k,
                                              ushort_t* __restrict__ wt) {
    int t    = blockIdx.x * 256 + threadIdx.x;
    int ic   = t & 127;
    int oc   = (t >> 7) & 255;
    int khkw = t >> 15;
    wt[t] = f32_to_bf16(k[((size_t)(khkw * CIN + ic)) * COUT + oc]);
}

// ---------- Main: 256x256 8-phase implicit-GEMM bf16 MFMA conv ----------
// Round-2-verified core. Single change: q0's B-fragment reads split — cf0/1 read
// pre-barrier, cf2/3 deferred into the middle of q0's MFMA cluster (race-free:
// b2/b3 consumed before q0-end barrier; buf[cur].B only overwritten by q2's
// stage issue, which is barrier-separated). Smooths the 12-read q0 burst to 8.

__device__ __forceinline__ int aoffK(int t) {
    int tap = t >> 1;
    return ((tap / 3) * WP + (tap % 3)) * CIN + (t & 1) * 64;
}
__device__ __forceinline__ int boffK(int t) {
    int tap = t >> 1;
    return tap * (COUT * CIN) + (t & 1) * 64;
}

__global__ __launch_bounds__(512, 2) void conv_mfma8(const ushort_t* __restrict__ pad,
                                                     const ushort_t* __restrict__ wt,
                                                     const float* __restrict__ bias,
                                                     float* __restrict__ out) {
    __shared__ __align__(16) ushort_t lds[65536];   // 128 KiB

    const int tid  = threadIdx.x;
    const int wid  = tid >> 6;
    const int lane = tid & 63;
    const int wm   = wid >> 2;       // 0..1 : 128-row band
    const int wn   = wid & 3;        // 0..3 : 64-col band
    const int bid  = blockIdx.x;
    const int bm   = (bid & 7) * 196 + (bid >> 3);   // XCD swizzle, 1568 % 8 == 0

    // ---- staging source pointers (pre-swizzled per-lane global addresses) ----
    const int trow = tid >> 3;              // 0..63 : row within a 64-row issue slice
    const int lc   = (tid & 7) ^ (trow & 7);  // logical chunk for this thread's physical slot

    const ushort_t* srcA[4];                // i = half*2 + issue  (rows i*64+trow of the 256-row tile)
    const ushort_t* srcB[4];
#pragma unroll
    for (int i = 0; i < 4; ++i) {
        int m  = bm * BM + i * 64 + trow;
        int n  = m / HW;
        int r  = m % HW;
        int oh = r / W;
        int ow = r % W;
        srcA[i] = pad + ((size_t)((n * HP + oh) * WP + ow)) * CIN + lc * 8;
        int oc = i * 64 + trow;
        srcB[i] = wt + (size_t)oc * CIN + lc * 8;
    }
    const int dstSlot = wid * 512;          // ushort elems within an issue slice (wave-uniform)

#define STAGE_A(tile, half)                                                                         \
    { int _o = aoffK(tile); int _b = ((tile) & 1) * 32768 + (half) * 8192 + dstSlot;                \
      __builtin_amdgcn_global_load_lds((gptr_t)(srcA[(half)*2+0] + _o), (lptr_t)&lds[_b       ], 16, 0, 0); \
      __builtin_amdgcn_global_load_lds((gptr_t)(srcA[(half)*2+1] + _o), (lptr_t)&lds[_b + 4096], 16, 0, 0); }
#define STAGE_B(tile, half)                                                                         \
    { int _o = boffK(tile); int _b = ((tile) & 1) * 32768 + 16384 + (half) * 8192 + dstSlot;        \
      __builtin_amdgcn_global_load_lds((gptr_t)(srcB[(half)*2+0] + _o), (lptr_t)&lds[_b       ], 16, 0, 0); \
      __builtin_amdgcn_global_load_lds((gptr_t)(srcB[(half)*2+1] + _o), (lptr_t)&lds[_b + 4096], 16, 0, 0); }

    // ---- read-side constants (ushort elems; row = 64 elems = 128 B) ----
    const int aBase = wm * 8192 + (lane & 15) * 64;
    const int bBase = 16384 + (wn >> 1) * 8192 + ((wn & 1) * 64 + (lane & 15)) * 64;
    int cOff[2];
#pragma unroll
    for (int ks = 0; ks < 2; ++ks)
        cOff[ks] = ((ks * 4 + (lane >> 4)) ^ (lane & 7)) * 8;

    floatx4 acc[8][4];
#pragma unroll
    for (int i = 0; i < 8; ++i)
#pragma unroll
        for (int j = 0; j < 4; ++j) acc[i][j] = (floatx4)0.0f;

    // ---- prologue: tile0 fully + B(tile1); wait tile0 (allow B(1)'s 4 loads in flight) ----
    STAGE_A(0, 0); STAGE_A(0, 1); STAGE_B(0, 0); STAGE_B(0, 1);
    STAGE_B(1, 0); STAGE_B(1, 1);
    asm volatile("s_waitcnt vmcnt(4)" ::: "memory");
    __builtin_amdgcn_s_barrier();

    // ---- main loop ----
    for (int t = 0; t < NT; ++t) {
        const int bufb = (t & 1) * 32768;
        bf16x8 bfr[4][2];
#pragma unroll
        for (int q = 0; q < 4; ++q) {
            bf16x8 af[2][2];
#pragma unroll
            for (int rfl = 0; rfl < 2; ++rfl)
#pragma unroll
                for (int ks = 0; ks < 2; ++ks)
                    af[rfl][ks] = *reinterpret_cast<const bf16x8*>(&lds[bufb + aBase + (2 * q + rfl) * 1024 + cOff[ks]]);
            if (q == 0) {
#pragma unroll
                for (int cf = 0; cf < 2; ++cf)      // cf0/1 pre-barrier; cf2/3 deferred
#pragma unroll
                    for (int ks = 0; ks < 2; ++ks)
                        bfr[cf][ks] = *reinterpret_cast<const bf16x8*>(&lds[bufb + bBase + cf * 1024 + cOff[ks]]);
            }
            if (q == 0 && t + 1 < NT) STAGE_A(t + 1, 0);
            if (q == 1 && t + 1 < NT) STAGE_A(t + 1, 1);
            if (q == 2 && t + 2 < NT) STAGE_B(t + 2, 0);
            if (q == 3 && t + 2 < NT) STAGE_B(t + 2, 1);
            __builtin_amdgcn_s_barrier();
            __builtin_amdgcn_s_setprio(1);
            if (q == 0) {
                // first half: cf0/1 MFMAs while b2/b3 reads issue mid-cluster
#pragma unroll
                for (int rfl = 0; rfl < 2; ++rfl)
#pragma unroll
                    for (int cf = 0; cf < 2; ++cf)
#pragma unroll
                        for (int ks = 0; ks < 2; ++ks)
                            acc[rfl][cf] = __builtin_amdgcn_mfma_f32_16x16x32_bf16(
                                af[rfl][ks], bfr[cf][ks], acc[rfl][cf], 0, 0, 0);
#pragma unroll
                for (int cf = 2; cf < 4; ++cf)      // deferred B reads (smooths q0 burst)
#pragma unroll
                    for (int ks = 0; ks < 2; ++ks)
                        bfr[cf][ks] = *reinterpret_cast<const bf16x8*>(&lds[bufb + bBase + cf * 1024 + cOff[ks]]);
#pragma unroll
                for (int rfl = 0; rfl < 2; ++rfl)
#pragma unroll
                    for (int cf = 2; cf < 4; ++cf)
#pragma unroll
                        for (int ks = 0; ks < 2; ++ks)
                            acc[rfl][cf] = __builtin_amdgcn_mfma_f32_16x16x32_bf16(
                                af[rfl][ks], bfr[cf][ks], acc[rfl][cf], 0, 0, 0);
            } else {
#pragma unroll
                for (int rfl = 0; rfl < 2; ++rfl)
#pragma unroll
                    for (int cf = 0; cf < 4; ++cf)
#pragma unroll
                        for (int ks = 0; ks < 2; ++ks)
                            acc[2 * q + rfl][cf] = __builtin_amdgcn_mfma_f32_16x16x32_bf16(
                                af[rfl][ks], bfr[cf][ks], acc[2 * q + rfl][cf], 0, 0, 0);
            }
            __builtin_amdgcn_s_setprio(0);
            if (q == 3) {
                if (t < NT - 2)       { asm volatile("s_waitcnt vmcnt(4)" ::: "memory"); }
                else if (t == NT - 2) { asm volatile("s_waitcnt vmcnt(0)" ::: "memory"); }
            }
            __builtin_amdgcn_s_barrier();
        }
    }

    // ---- epilogue: C/D map col=lane&15, row=(lane>>4)*4+reg ----
    const int col0 = wn * 64 + (lane & 15);
    const int row0 = bm * BM + wm * 128 + (lane >> 4) * 4;
    float bv[4];
#pragma unroll
    for (int cf = 0; cf < 4; ++cf) bv[cf] = bias[col0 + cf * 16];
#pragma unroll
    for (int rf = 0; rf < 8; ++rf)
#pragma unroll
        for (int cf = 0; cf < 4; ++cf)
#pragma unroll
            for (int r = 0; r < 4; ++r)
                out[(size_t)(row0 + rf * 16 + r) * COUT + col0 + cf * 16] = acc[rf][cf][r] + bv[cf];
#undef STAGE_A
#undef STAGE_B
}

extern "C" void kernel_launch(void* const* d_in, const int* in_sizes, int n_in,
                              void* d_out, int out_size, void* d_ws, size_t ws_size,
                              hipStream_t stream) {
    const float* input = (const float*)d_in[0];
    const float* kern  = (const float*)d_in[1];
    const float* bias  = (const float*)d_in[2];
    float* out         = (float*)d_out;

    ushort_t* pad = (ushort_t*)d_ws;                          // 106,463,232 B
    ushort_t* wt  = pad + (size_t)NIMG * HP * WP * CIN;       // + 589,824 B

    prepad_input<<<25992, 256, 0, stream>>>(input, pad);
    wtrans<<<1152, 256, 0, stream>>>(kern, wt);
    conv_mfma8<<<1568, 512, 0, stream>>>(pad, wt, bias, out); // 1568 = 401408/256, %8==0
}

// Round 8
// 358.641 us; speedup vs baseline: 1.1792x; 1.0101x over previous
//
#include <hip/hip_runtime.h>

typedef __attribute__((ext_vector_type(4))) float   floatx4;
typedef __attribute__((ext_vector_type(8))) __bf16  bf16x8;
typedef unsigned short ushort_t;
typedef __attribute__((ext_vector_type(8))) ushort_t ushortx8;

typedef const unsigned int __attribute__((address_space(1)))* gptr_t;
typedef unsigned int __attribute__((address_space(3)))* lptr_t;

#define NIMG 32
#define H    112
#define W    112
#define CIN  128
#define COUT 256
#define HP   114
#define WP   114
#define HW   12544      // H*W, = 49*256 so every 256-row tile stays in one image

#define BM 256
#define BN 256
#define BK 64
#define NT 18           // K = 3*3*128 = 1152 = 18*64

#define PREPAD_BLOCKS 12996   // 32*114*114*8 / 256  (32B per thread)
#define WTRANS_BLOCKS 1152    // 3*3*256*128 / 256

// ---------- fp32 -> bf16 (round-to-nearest-even) ----------
__device__ __forceinline__ ushort_t f32_to_bf16(float f) {
    unsigned u = __float_as_uint(f);
    unsigned r = 0x7fffu + ((u >> 16) & 1u);
    return (ushort_t)((u + r) >> 16);
}

// ---------- Fused prepass ----------
// blocks [0, PREPAD_BLOCKS): convert + zero-pad input to [32][114][114][128] bf16,
//   32 B output per thread (16 channels).
// blocks [PREPAD_BLOCKS, +WTRANS_BLOCKS): kernel (3,3,128,256) HWIO -> bf16 [kh][kw][oc][ic].
__global__ __launch_bounds__(256) void prepass_fused(const float* __restrict__ in,
                                                     const float* __restrict__ k,
                                                     ushort_t* __restrict__ pad,
                                                     ushort_t* __restrict__ wt) {
    int bid = blockIdx.x;
    if (bid < PREPAD_BLOCKS) {
        int u    = bid * 256 + threadIdx.x;
        int ic16 = u & 7;             // 16-channel chunk
        int sp   = u >> 3;            // n*HP*WP + ih*WP + iw
        int iw   = sp % WP;
        int sp2  = sp / WP;
        int ih   = sp2 % HP;
        int n    = sp2 / HP;
        ushortx8 v0, v1;
        if (ih >= 1 && ih <= H && iw >= 1 && iw <= W) {
            const float* src = in + ((size_t)((n * H + (ih - 1)) * W + (iw - 1))) * CIN + ic16 * 16;
            floatx4 a = *reinterpret_cast<const floatx4*>(src);
            floatx4 b = *reinterpret_cast<const floatx4*>(src + 4);
            floatx4 c = *reinterpret_cast<const floatx4*>(src + 8);
            floatx4 d = *reinterpret_cast<const floatx4*>(src + 12);
#pragma unroll
            for (int j = 0; j < 4; ++j) {
                v0[j] = f32_to_bf16(a[j]); v0[4 + j] = f32_to_bf16(b[j]);
                v1[j] = f32_to_bf16(c[j]); v1[4 + j] = f32_to_bf16(d[j]);
            }
        } else {
#pragma unroll
            for (int j = 0; j < 8; ++j) { v0[j] = 0; v1[j] = 0; }
        }
        ushortx8* dst = reinterpret_cast<ushortx8*>(pad) + ((size_t)sp * 16 + ic16 * 2);
        dst[0] = v0;
        dst[1] = v1;
    } else {
        int t    = (bid - PREPAD_BLOCKS) * 256 + threadIdx.x;
        int ic   = t & 127;
        int oc   = (t >> 7) & 255;
        int khkw = t >> 15;
        wt[t] = f32_to_bf16(k[((size_t)(khkw * CIN + ic)) * COUT + oc]);
    }
}

// ---------- Main: 256x256 8-phase implicit-GEMM bf16 MFMA conv ----------
// (byte-identical to the round-5 PASSING kernel; do not touch)

__device__ __forceinline__ int aoffK(int t) {
    int tap = t >> 1;
    return ((tap / 3) * WP + (tap % 3)) * CIN + (t & 1) * 64;
}
__device__ __forceinline__ int boffK(int t) {
    int tap = t >> 1;
    return tap * (COUT * CIN) + (t & 1) * 64;
}

__global__ __launch_bounds__(512, 2) void conv_mfma8(const ushort_t* __restrict__ pad,
                                                     const ushort_t* __restrict__ wt,
                                                     const float* __restrict__ bias,
                                                     float* __restrict__ out) {
    __shared__ __align__(16) ushort_t lds[65536];   // 128 KiB

    const int tid  = threadIdx.x;
    const int wid  = tid >> 6;
    const int lane = tid & 63;
    const int wm   = wid >> 2;       // 0..1 : 128-row band
    const int wn   = wid & 3;        // 0..3 : 64-col band
    const int bid  = blockIdx.x;
    const int bm   = (bid & 7) * 196 + (bid >> 3);   // XCD swizzle, 1568 % 8 == 0

    // ---- staging source pointers (pre-swizzled per-lane global addresses) ----
    const int trow = tid >> 3;              // 0..63 : row within a 64-row issue slice
    const int lc   = (tid & 7) ^ (trow & 7);  // logical chunk for this thread's physical slot

    const ushort_t* srcA[4];                // i = half*2 + issue  (rows i*64+trow of the 256-row tile)
    const ushort_t* srcB[4];
#pragma unroll
    for (int i = 0; i < 4; ++i) {
        int m  = bm * BM + i * 64 + trow;
        int n  = m / HW;
        int r  = m % HW;
        int oh = r / W;
        int ow = r % W;
        srcA[i] = pad + ((size_t)((n * HP + oh) * WP + ow)) * CIN + lc * 8;
        int oc = i * 64 + trow;
        srcB[i] = wt + (size_t)oc * CIN + lc * 8;
    }
    const int dstSlot = wid * 512;          // ushort elems within an issue slice (wave-uniform)

#define STAGE_A(tile, half)                                                                         \
    { int _o = aoffK(tile); int _b = ((tile) & 1) * 32768 + (half) * 8192 + dstSlot;                \
      __builtin_amdgcn_global_load_lds((gptr_t)(srcA[(half)*2+0] + _o), (lptr_t)&lds[_b       ], 16, 0, 0); \
      __builtin_amdgcn_global_load_lds((gptr_t)(srcA[(half)*2+1] + _o), (lptr_t)&lds[_b + 4096], 16, 0, 0); }
#define STAGE_B(tile, half)                                                                         \
    { int _o = boffK(tile); int _b = ((tile) & 1) * 32768 + 16384 + (half) * 8192 + dstSlot;        \
      __builtin_amdgcn_global_load_lds((gptr_t)(srcB[(half)*2+0] + _o), (lptr_t)&lds[_b       ], 16, 0, 0); \
      __builtin_amdgcn_global_load_lds((gptr_t)(srcB[(half)*2+1] + _o), (lptr_t)&lds[_b + 4096], 16, 0, 0); }

    // ---- read-side constants (ushort elems; row = 64 elems = 128 B) ----
    const int aBase = wm * 8192 + (lane & 15) * 64;
    const int bBase = 16384 + (wn >> 1) * 8192 + ((wn & 1) * 64 + (lane & 15)) * 64;
    int cOff[2];
#pragma unroll
    for (int ks = 0; ks < 2; ++ks)
        cOff[ks] = ((ks * 4 + (lane >> 4)) ^ (lane & 7)) * 8;

    floatx4 acc[8][4];
#pragma unroll
    for (int i = 0; i < 8; ++i)
#pragma unroll
        for (int j = 0; j < 4; ++j) acc[i][j] = (floatx4)0.0f;

    // ---- prologue: tile0 fully + B(tile1); wait tile0 (allow B(1)'s 4 loads in flight) ----
    STAGE_A(0, 0); STAGE_A(0, 1); STAGE_B(0, 0); STAGE_B(0, 1);
    STAGE_B(1, 0); STAGE_B(1, 1);
    asm volatile("s_waitcnt vmcnt(4)" ::: "memory");
    __builtin_amdgcn_s_barrier();

    // ---- main loop ----
    for (int t = 0; t < NT; ++t) {
        const int bufb = (t & 1) * 32768;
        bf16x8 bfr[4][2];
#pragma unroll
        for (int q = 0; q < 4; ++q) {
            bf16x8 af[2][2];
#pragma unroll
            for (int rfl = 0; rfl < 2; ++rfl)
#pragma unroll
                for (int ks = 0; ks < 2; ++ks)
                    af[rfl][ks] = *reinterpret_cast<const bf16x8*>(&lds[bufb + aBase + (2 * q + rfl) * 1024 + cOff[ks]]);
            if (q == 0) {
#pragma unroll
                for (int cf = 0; cf < 2; ++cf)      // cf0/1 pre-barrier; cf2/3 deferred
#pragma unroll
                    for (int ks = 0; ks < 2; ++ks)
                        bfr[cf][ks] = *reinterpret_cast<const bf16x8*>(&lds[bufb + bBase + cf * 1024 + cOff[ks]]);
            }
            if (q == 0 && t + 1 < NT) STAGE_A(t + 1, 0);
            if (q == 1 && t + 1 < NT) STAGE_A(t + 1, 1);
            if (q == 2 && t + 2 < NT) STAGE_B(t + 2, 0);
            if (q == 3 && t + 2 < NT) STAGE_B(t + 2, 1);
            __builtin_amdgcn_s_barrier();
            __builtin_amdgcn_s_setprio(1);
            if (q == 0) {
                // first half: cf0/1 MFMAs while b2/b3 reads issue mid-cluster
#pragma unroll
                for (int rfl = 0; rfl < 2; ++rfl)
#pragma unroll
                    for (int cf = 0; cf < 2; ++cf)
#pragma unroll
                        for (int ks = 0; ks < 2; ++ks)
                            acc[rfl][cf] = __builtin_amdgcn_mfma_f32_16x16x32_bf16(
                                af[rfl][ks], bfr[cf][ks], acc[rfl][cf], 0, 0, 0);
#pragma unroll
                for (int cf = 2; cf < 4; ++cf)      // deferred B reads (smooths q0 burst)
#pragma unroll
                    for (int ks = 0; ks < 2; ++ks)
                        bfr[cf][ks] = *reinterpret_cast<const bf16x8*>(&lds[bufb + bBase + cf * 1024 + cOff[ks]]);
#pragma unroll
                for (int rfl = 0; rfl < 2; ++rfl)
#pragma unroll
                    for (int cf = 2; cf < 4; ++cf)
#pragma unroll
                        for (int ks = 0; ks < 2; ++ks)
                            acc[rfl][cf] = __builtin_amdgcn_mfma_f32_16x16x32_bf16(
                                af[rfl][ks], bfr[cf][ks], acc[rfl][cf], 0, 0, 0);
            } else {
#pragma unroll
                for (int rfl = 0; rfl < 2; ++rfl)
#pragma unroll
                    for (int cf = 0; cf < 4; ++cf)
#pragma unroll
                        for (int ks = 0; ks < 2; ++ks)
                            acc[2 * q + rfl][cf] = __builtin_amdgcn_mfma_f32_16x16x32_bf16(
                                af[rfl][ks], bfr[cf][ks], acc[2 * q + rfl][cf], 0, 0, 0);
            }
            __builtin_amdgcn_s_setprio(0);
            if (q == 3) {
                if (t < NT - 2)       { asm volatile("s_waitcnt vmcnt(4)" ::: "memory"); }
                else if (t == NT - 2) { asm volatile("s_waitcnt vmcnt(0)" ::: "memory"); }
            }
            __builtin_amdgcn_s_barrier();
        }
    }

    // ---- epilogue: C/D map col=lane&15, row=(lane>>4)*4+reg ----
    const int col0 = wn * 64 + (lane & 15);
    const int row0 = bm * BM + wm * 128 + (lane >> 4) * 4;
    float bv[4];
#pragma unroll
    for (int cf = 0; cf < 4; ++cf) bv[cf] = bias[col0 + cf * 16];
#pragma unroll
    for (int rf = 0; rf < 8; ++rf)
#pragma unroll
        for (int cf = 0; cf < 4; ++cf)
#pragma unroll
            for (int r = 0; r < 4; ++r)
                out[(size_t)(row0 + rf * 16 + r) * COUT + col0 + cf * 16] = acc[rf][cf][r] + bv[cf];
#undef STAGE_A
#undef STAGE_B
}

extern "C" void kernel_launch(void* const* d_in, const int* in_sizes, int n_in,
                              void* d_out, int out_size, void* d_ws, size_t ws_size,
                              hipStream_t stream) {
    const float* input = (const float*)d_in[0];
    const float* kern  = (const float*)d_in[1];
    const float* bias  = (const float*)d_in[2];
    float* out         = (float*)d_out;

    ushort_t* pad = (ushort_t*)d_ws;                          // 106,463,232 B
    ushort_t* wt  = pad + (size_t)NIMG * HP * WP * CIN;       // + 589,824 B

    prepass_fused<<<PREPAD_BLOCKS + WTRANS_BLOCKS, 256, 0, stream>>>(input, kern, pad, wt);
    conv_mfma8<<<1568, 512, 0, stream>>>(pad, wt, bias, out); // 1568 = 401408/256, %8==0
}